// Round 9
// baseline (94.529 us; speedup 1.0000x reference)
//
#include <hip/hip_runtime.h>
#include <math.h>

// SplitBruteForceAntisymmetrize: N=6 (720 perms), D=3, HID=64, BATCH=2048.
// Math (R3+R4, measured absmax 0.1875):
//   F[j][i] = exp2(K*c[j][i]) (K=2log2e, b1 folded into col 0); 2^{preact'} =
//   prod_i F[perm(i)][i]; tanh = 1 - 2/(E+1); sum_p sign_p = 0.
//   Pair {a<b} after 4-slot prefix P: d = P*(v-u)/(P^2*u*v + P*(u+v) + 1).
//   Depth-3 triple-combine: 3 children merged over common denominator ->
//   ONE rcp + ONE fp64 add per 6 perms. Signed fold in fp64 (R2 lesson:
//   S ~ 1e-5 vs O(1) terms; fp32 running sums are fatal).
//   Named-member tables via if-constexpr getters (R8): no arrays -> no alloca
//   -> no scratch (R7 rocprof: VGPR_Count=88 proved LLVM put arrays in
//   scratch; R8 removed it - profiled dur 60 -> <39 us).
// R9 (single change): UNPACK to 1 job/wave. gfx950 packed f32 is 4cyc (peak
//   157 TF = scalar SIMD-32 rate, m07) -> packing halves instructions but not
//   cycles, while capping the machine at 2048 waves = 2 waves/SIMD (measured
//   stall factor 1.39). Scalar 1-job waves: 4096 waves = 4 waves/SIMD, same
//   total issue cycles, 2x latency hiding. Scalar live set ~110 VGPR fits the
//   128 cap of __launch_bounds__(256,4) now that everything is named/SROA'd.
//   grid 1024 = exactly 4 blocks/CU, zero tail.
// Overflow: den = prod of 6 (E+1)-like factors <= ~2^93 at data tails < 2^127.

__device__ __forceinline__ float fexp2(float x) {
#if __has_builtin(__builtin_amdgcn_exp2f)
    return __builtin_amdgcn_exp2f(x);
#else
    return exp2f(x);
#endif
}
__device__ __forceinline__ float frcp(float x) {
#if __has_builtin(__builtin_amdgcn_rcpf)
    return __builtin_amdgcn_rcpf(x);
#else
    return 1.0f / x;
#endif
}

constexpr int lowest_free(unsigned used) {
    for (int j = 0; j < 6; ++j)
        if (!(used & (1u << j))) return j;
    return -1;
}

// ---- named-member tables (NO arrays anywhere -> no alloca -> no scratch) ----
#define FJI_LIST(X) X(0,0) X(0,1) X(0,2) X(0,3) X(1,0) X(1,1) X(1,2) X(1,3) \
                    X(2,0) X(2,1) X(2,2) X(2,3) X(3,0) X(3,1) X(3,2) X(3,3) \
                    X(4,0) X(4,1) X(4,2) X(4,3) X(5,0) X(5,1) X(5,2) X(5,3)
#define J6_LIST(X) X(0) X(1) X(2) X(3) X(4) X(5)
#define PAIR_LIST(X) X(0,1) X(0,2) X(0,3) X(0,4) X(0,5) X(1,2) X(1,3) X(1,4) \
                     X(1,5) X(2,3) X(2,4) X(2,5) X(3,4) X(3,5) X(4,5)
#define WC_LIST(X) X(0) X(1) X(2) X(3) X(4) X(5) X(6) X(7) X(8) X(9) X(10) \
                   X(11) X(12) X(13) X(14) X(15) X(16) X(17)

struct Tbl {
#define M(j,i) float F##j##_##i;
    FJI_LIST(M)
#undef M
#define M(j) float FA##j; float FB##j; float G##j;
    J6_LIST(M)
#undef M
#define M(a,b) float W##a##b; float S##a##b; float Q##a##b;
    PAIR_LIST(M)
#undef M
};

template <int J, int I> __device__ __forceinline__ float getF(const Tbl& T) {
#define M(j,i) if constexpr (J==j && I==i) return T.F##j##_##i;
    FJI_LIST(M)
#undef M
    __builtin_unreachable();
}
template <int J, int I> __device__ __forceinline__ void setF(Tbl& T, float v) {
#define M(j,i) if constexpr (J==j && I==i) T.F##j##_##i = v;
    FJI_LIST(M)
#undef M
}
template <int J> __device__ __forceinline__ float getFA(const Tbl& T) {
#define M(j) if constexpr (J==j) return T.FA##j;
    J6_LIST(M)
#undef M
    __builtin_unreachable();
}
template <int J> __device__ __forceinline__ void setFA(Tbl& T, float v) {
#define M(j) if constexpr (J==j) T.FA##j = v;
    J6_LIST(M)
#undef M
}
template <int J> __device__ __forceinline__ float getFB(const Tbl& T) {
#define M(j) if constexpr (J==j) return T.FB##j;
    J6_LIST(M)
#undef M
    __builtin_unreachable();
}
template <int J> __device__ __forceinline__ void setFB(Tbl& T, float v) {
#define M(j) if constexpr (J==j) T.FB##j = v;
    J6_LIST(M)
#undef M
}
template <int J> __device__ __forceinline__ float getG(const Tbl& T) {
#define M(j) if constexpr (J==j) return T.G##j;
    J6_LIST(M)
#undef M
    __builtin_unreachable();
}
template <int J> __device__ __forceinline__ void setG(Tbl& T, float v) {
#define M(j) if constexpr (J==j) T.G##j = v;
    J6_LIST(M)
#undef M
}
template <int A, int B> __device__ __forceinline__ float getW(const Tbl& T) {
#define M(a,b) if constexpr (A==a && B==b) return T.W##a##b;
    PAIR_LIST(M)
#undef M
    __builtin_unreachable();
}
template <int A, int B> __device__ __forceinline__ void setW(Tbl& T, float v) {
#define M(a,b) if constexpr (A==a && B==b) T.W##a##b = v;
    PAIR_LIST(M)
#undef M
}
template <int A, int B> __device__ __forceinline__ float getS(const Tbl& T) {
#define M(a,b) if constexpr (A==a && B==b) return T.S##a##b;
    PAIR_LIST(M)
#undef M
    __builtin_unreachable();
}
template <int A, int B> __device__ __forceinline__ void setS(Tbl& T, float v) {
#define M(a,b) if constexpr (A==a && B==b) T.S##a##b = v;
    PAIR_LIST(M)
#undef M
}
template <int A, int B> __device__ __forceinline__ float getQ(const Tbl& T) {
#define M(a,b) if constexpr (A==a && B==b) return T.Q##a##b;
    PAIR_LIST(M)
#undef M
    __builtin_unreachable();
}
template <int A, int B> __device__ __forceinline__ void setQ(Tbl& T, float v) {
#define M(a,b) if constexpr (A==a && B==b) T.Q##a##b = v;
    PAIR_LIST(M)
#undef M
}

// per-lane weights, pre-scaled by K = 2*log2(e); named scalars only
struct Wgt {
#define M(r) float c##r;
    WC_LIST(M)
#undef M
    float b1s;
};
template <int R> __device__ __forceinline__ float getWC(const Wgt& W) {
#define M(r) if constexpr (R==r) return W.c##r;
    WC_LIST(M)
#undef M
    __builtin_unreachable();
}

// ---- setup: c -> exp2 -> F/FA/FB/G, then pair tables W/S/Q ----
template <int J, int I>
__device__ __forceinline__ void setupJI(Tbl& T, const Wgt& Wg,
                                        float x0, float x1, float x2) {
    float c = x0 * getWC<3*I+0>(Wg) + x1 * getWC<3*I+1>(Wg) + x2 * getWC<3*I+2>(Wg);
    if constexpr (I == 0) c += Wg.b1s;
    float e = fexp2(c);
    if constexpr (I < 4) setF<J, I>(T, e);
    else if constexpr (I == 4) setFA<J>(T, e);
    else { setFB<J>(T, e); setG<J>(T, getFA<J>(T) * e); }
}

template <int J>
__device__ __forceinline__ void setupJ(Tbl& T, const Wgt& Wg, const float* xp) {
    float x0 = xp[3*J+0];
    float x1 = xp[3*J+1];
    float x2 = xp[3*J+2];
    setupJI<J,0>(T, Wg, x0, x1, x2);
    setupJI<J,1>(T, Wg, x0, x1, x2);
    setupJI<J,2>(T, Wg, x0, x1, x2);
    setupJI<J,3>(T, Wg, x0, x1, x2);
    setupJI<J,4>(T, Wg, x0, x1, x2);
    setupJI<J,5>(T, Wg, x0, x1, x2);
}

template <int A, int B>
__device__ __forceinline__ void setupPair(Tbl& T) {
    float u = getFA<A>(T) * getFB<B>(T);   // (a@4, b@5)
    float v = getFA<B>(T) * getFB<A>(T);   // (b@4, a@5)
    setW<A,B>(T, v - u);
    setS<A,B>(T, u + v);
    setQ<A,B>(T, getG<A>(T) * getG<B>(T));
}

// ---- DFS over slots 0..2; P = running product of F factors ----
template <int LVL, unsigned USED, int PAR>
struct Node {
    template <int J>
    static __device__ __forceinline__ void step(const Tbl& T, float P,
                                                double& a0, double& a1) {
        if constexpr ((USED & (1u << J)) == 0) {
            constexpr int par2 = PAR ^ (__builtin_popcount(USED >> (J + 1)) & 1);
            if constexpr (LVL == 0)
                Node<1, (1u << J), par2>::go(T, getF<J,0>(T), a0, a1);
            else
                Node<LVL + 1, USED | (1u << J), par2>::go(T, P * getF<J,LVL>(T), a0, a1);
        }
    }
    static __device__ __forceinline__ void go(const Tbl& T, float P,
                                              double& a0, double& a1) {
        step<0>(T, P, a0, a1);
        step<1>(T, P, a0, a1);
        step<2>(T, P, a0, a1);
        step<3>(T, P, a0, a1);
        step<4>(T, P, a0, a1);
        step<5>(T, P, a0, a1);
    }
};

// Depth-3 node: slots 0-2 placed; 3 free -> 3 children (x@slot3), each leaving
// transposition pair {a<b}; merged over common denominator.
template <unsigned USED, int PAR>
struct Node<3, USED, PAR> {
    template <int X, int A, int B>
    static __device__ __forceinline__ float child_den(const Tbl& T, float P3,
                                                      float& n) {
        float P4 = P3 * getF<X,3>(T);
        float Q  = P4 * P4;
        n = P4 * getW<A,B>(T);
        return fmaf(Q, getQ<A,B>(T), fmaf(P4, getS<A,B>(T), 1.0f));
    }
    template <int X, int A, int B>
    static constexpr int child_sign() {
        constexpr unsigned U4 = USED | (1u << X);
        constexpr int inv_x = __builtin_popcount(USED >> (X + 1));
        constexpr int inv_a = __builtin_popcount(U4 >> (A + 1));
        constexpr int inv_b = __builtin_popcount((U4 | (1u << A)) >> (B + 1));
        return (PAR ^ ((inv_x + inv_a + inv_b) & 1));
    }
    static __device__ __forceinline__ void go(const Tbl& T, float P3,
                                              double& a0, double& a1) {
        constexpr int x0 = lowest_free(USED);
        constexpr int x1 = lowest_free(USED | (1u << x0));
        constexpr int x2 = lowest_free(USED | (1u << x0) | (1u << x1));

        float n0, n1, n2;
        float den0 = child_den<x0, x1, x2>(T, P3, n0);
        float den1 = child_den<x1, x0, x2>(T, P3, n1);
        float den2 = child_den<x2, x0, x1>(T, P3, n2);

        float n0s = child_sign<x0, x1, x2>() ? -n0 : n0;
        float n1s = child_sign<x1, x0, x2>() ? -n1 : n1;
        float n2s = child_sign<x2, x0, x1>() ? -n2 : n2;

        float d01 = den0 * den1;
        float den = d01 * den2;
        float t01 = fmaf(n0s, den1, n1s * den0);
        float num = fmaf(t01, den2, n2s * d01);
        float r = num * frcp(den);
        if constexpr (USED & 1) a1 += (double)r;
        else                    a0 += (double)r;
    }
};

__global__ __launch_bounds__(256, 4) void antisym_kernel(
    const float* __restrict__ x1, const float* __restrict__ x2,
    const float* __restrict__ W1a, const float* __restrict__ b1a,
    const float* __restrict__ W2a,
    const float* __restrict__ W1b, const float* __restrict__ b1b,
    const float* __restrict__ W2b,
    float* __restrict__ out, int B) {
    __shared__ float lds_log[4];

    const int lane = threadIdx.x & 63;
    const int wave = threadIdx.x >> 6;
    const int b = blockIdx.x * 2 + (wave >> 1);  // waves 0,1 -> b0; 2,3 -> b0+1
    const int ch = wave & 1;

    if (b < B) {
        const float* x  = ch ? x2  : x1;
        const float* W1 = ch ? W1b : W1a;
        const float* b1 = ch ? b1b : b1a;
        const float* W2 = ch ? W2b : W2a;

        const float K = 2.8853900817779268f;  // 2*log2(e)

        Wgt Wg;
#define M(r) Wg.c##r = W1[r * 64 + lane] * K;
        WC_LIST(M)
#undef M
        Wg.b1s = b1[lane] * K;
        const float w2v = W2[lane];

        const float* xp = x + b * 18;

        Tbl T;
        setupJ<0>(T, Wg, xp);
        setupJ<1>(T, Wg, xp);
        setupJ<2>(T, Wg, xp);
        setupJ<3>(T, Wg, xp);
        setupJ<4>(T, Wg, xp);
        setupJ<5>(T, Wg, xp);
#define M(a,b) setupPair<a,b>(T);
        PAIR_LIST(M)
#undef M

        double acc0 = 0.0, acc1 = 0.0;
        Node<0, 0u, 0>::go(T, 1.0f, acc0, acc1);

        // psi = -2 * w2 * S ; b2 contributes b2*sum(signs) = 0 exactly
        double v = (double)w2v * (acc0 + acc1) * -2.0;
#pragma unroll
        for (int off = 32; off > 0; off >>= 1) v += __shfl_xor(v, off, 64);

        if (lane == 0) lds_log[wave] = logf(fabsf((float)v));
    }
    __syncthreads();
    if (threadIdx.x < 2) {
        int bb = blockIdx.x * 2 + threadIdx.x;
        if (bb < B)
            out[bb] = lds_log[threadIdx.x * 2] + lds_log[threadIdx.x * 2 + 1];
    }
}

extern "C" void kernel_launch(void* const* d_in, const int* in_sizes, int n_in,
                              void* d_out, int out_size, void* d_ws, size_t ws_size,
                              hipStream_t stream) {
    const float* x1  = (const float*)d_in[0];
    const float* x2  = (const float*)d_in[1];
    const float* W1a = (const float*)d_in[2];
    const float* b1a = (const float*)d_in[3];
    const float* W2a = (const float*)d_in[4];
    // d_in[5] = b2a: contributes b2 * sum(signs) = 0 exactly
    const float* W1b = (const float*)d_in[6];
    const float* b1b = (const float*)d_in[7];
    const float* W2b = (const float*)d_in[8];
    // d_in[9] = b2b: same

    const int B = in_sizes[0] / 18;  // (B, 6, 3) flattened
    float* out = (float*)d_out;

    dim3 grid((B + 1) / 2), block(256);  // 4 waves/block, 1 (b,ch) job per wave
    hipLaunchKernelGGL(antisym_kernel, grid, block, 0, stream,
                       x1, x2, W1a, b1a, W2a, W1b, b1b, W2b, out, B);
}